// Round 14
// baseline (327.227 us; speedup 1.0000x reference)
//
#include <hip/hip_runtime.h>
#include <hip/hip_bf16.h>
#include <cstdint>
#include <cstddef>

#define E_EDGES 320000
#define NN 10000
#define NRELS 40
#define NB 30
#define HID 100
#define NHTOT (NN*HID)       // 1,000,000
#define R2 41                // 40 rels + root2 slot
#define KTOT 4224            // 41*100 = 4100 packed, padded to 33*128
#define NROWS_PAD 10048      // 157 blocks * 64 rows
#define SPLITK 4             // 132 kb-steps -> 33 per gy
#define KB_PER 33
#define RSPLIT 4
#define RPB (NRELS/RSPLIT)   // 10 rels per pass

typedef short bf16x8 __attribute__((ext_vector_type(8)));
typedef float f32x4 __attribute__((ext_vector_type(4)));
typedef float f32x2 __attribute__((ext_vector_type(2)));

__device__ inline ushort f2bf(float f) {
  uint x = __float_as_uint(f);
  return (ushort)((x + 0x7fffu + ((x >> 16) & 1u)) >> 16);
}
__device__ inline float bflo(uint u) { return __uint_as_float(u << 16); }
__device__ inline float bfhi(uint u) { return __uint_as_float(u & 0xffff0000u); }

// HW packed f32->bf16 RNE (v_cvt_pk_bf16_f32 via compiler)
__device__ inline uint pack2bf(float x, float y) {
  union { __hip_bfloat162 b; uint u; } cv;
  cv.b = __float22bfloat162_rn(make_float2(x, y));
  return cv.u;
}

__device__ inline void gload16(const void* g, void* l) {
  __builtin_amdgcn_global_load_lds(
      (const __attribute__((address_space(1))) void*)g,
      (__attribute__((address_space(3))) void*)l, 16, 0, 0);
}

// ---------------------------------------------------------------- edge meta
__global__ void k_count(const int* __restrict__ dst, const int* __restrict__ et,
                        int* __restrict__ cnt_nr, int* __restrict__ deg) {
  int e = blockIdx.x * blockDim.x + threadIdx.x;
  if (e >= E_EDGES) return;
  int d = dst[e], r = et[e];
  atomicAdd(&cnt_nr[d * NRELS + r], 1);
  atomicAdd(&deg[d], 1);
}

__global__ void k_scan(const int* __restrict__ deg, int* __restrict__ rowptr) {
  __shared__ int ssum[256];
  int t = threadIdx.x;
  const int per = (NN + 255) / 256;
  int base = t * per;
  int s = 0;
  for (int k = 0; k < per; ++k) { int i = base + k; if (i < NN) s += deg[i]; }
  ssum[t] = s; __syncthreads();
  for (int off = 1; off < 256; off <<= 1) {
    int v = (t >= off) ? ssum[t - off] : 0;
    __syncthreads();
    ssum[t] += v;
    __syncthreads();
  }
  int pre = (t == 0) ? 0 : ssum[t - 1];
  for (int k = 0; k < per; ++k) {
    int i = base + k;
    if (i < NN) { rowptr[i] = pre; pre += deg[i]; }
  }
  if (t == 255) rowptr[NN] = ssum[255];
}

// per-node scan over rels -> task descriptors desc[n*40+r] = {segment begin, cnt}
__global__ void k_pnr(const int* __restrict__ cnt_nr, const int* __restrict__ rowptr,
                      int2* __restrict__ desc) {
  int n = blockIdx.x * 256 + threadIdx.x;
  if (n >= NN) return;
  int s = rowptr[n];
  for (int r = 0; r < NRELS; ++r) {
    int c = cnt_nr[n * NRELS + r];
    desc[n * NRELS + r] = make_int2(s, c);
    s += c;
  }
}

// bucket edges sorted by (dst, rel): segment-contiguous in ebuf
__global__ void k_bucket(const int* __restrict__ src, const int* __restrict__ dst,
                         const int* __restrict__ et, const int2* __restrict__ desc,
                         int* __restrict__ fill_nr, int* __restrict__ ebuf) {
  int e = blockIdx.x * blockDim.x + threadIdx.x;
  if (e >= E_EDGES) return;
  int d = dst[e], r = et[e];
  int pos = desc[d * NRELS + r].x + atomicAdd(&fill_nr[d * NRELS + r], 1);
  ebuf[pos] = (src[e] << 6) | r;
}

// comp1 transpose -> comp1t[b][r] (contiguous in r for wave-uniform s_load)
__global__ void k_ct(const float* __restrict__ comp1, float* __restrict__ comp1t) {
  int i = blockIdx.x * 256 + threadIdx.x;
  if (i >= NRELS * NB) return;
  int r = i / NB, b = i - r * NB;
  comp1t[b * NRELS + r] = comp1[i];
}

// ---------------------------------------------------------------- W1 (bf16)
// RSPLIT=4 + float4 threads: acc[10] f32x4 = 40 VGPR -> total ~55, fits the
// allocator's 64-VGPR budget WITHOUT loop distribution (r13: VGPR=24 meant
// the compiler split the r-loop and re-streamed basis1 from L2/L3 ~5x,
// capping at 2.5 TB/s). 16B loads; passes 2-4 ride L3 (basis1 = 120MB).
__global__ __launch_bounds__(256) void k_w1b(const float* __restrict__ comp1t,
                                             const float* __restrict__ basis1,
                                             uint2* __restrict__ W1bf) {
  int t = threadIdx.x;
  int rbase = blockIdx.y * RPB;
  int i4 = blockIdx.x * 256 + t;
  if (i4 >= NHTOT / 4) return;
  f32x4 acc[RPB];
#pragma unroll
  for (int r = 0; r < RPB; ++r) acc[r] = (f32x4){0.f, 0.f, 0.f, 0.f};
  for (int b = 0; b < NB; ++b) {
    f32x4 v = ((const f32x4*)basis1)[(size_t)b * (NHTOT / 4) + i4];
    const float* ct = comp1t + b * NRELS + rbase;   // wave-uniform -> s_load
#pragma unroll
    for (int r = 0; r < RPB; ++r) {
      float c = ct[r];
      acc[r] += (f32x4){c, c, c, c} * v;
    }
  }
#pragma unroll
  for (int r = 0; r < RPB; ++r)
    W1bf[(size_t)(rbase + r) * (NHTOT / 4) + i4] =
        make_uint2(pack2bf(acc[r][0], acc[r][1]), pack2bf(acc[r][2], acc[r][3]));
}

// ---------------------------------------------------------------- W2 fp32 then packed Bt bf16
__global__ void k_w2(const float* __restrict__ comp2, const float* __restrict__ basis2,
                     float* __restrict__ W2f) {
  int i = blockIdx.x * 256 + threadIdx.x;
  if (i >= HID * HID) return;
  float v[NB];
#pragma unroll
  for (int b = 0; b < NB; ++b) v[b] = basis2[b * HID * HID + i];
  for (int r = 0; r < NRELS; ++r) {
    float a = 0.f;
#pragma unroll
    for (int b = 0; b < NB; ++b) a += comp2[r * NB + b] * v[b];
    W2f[r * HID * HID + i] = a;
  }
}

// Bt[col][kk] packed K: kk = r*100 + k  (r<40: W2f[r][k][col], r==40: root2[k][col])
__global__ void k_bt(const float* __restrict__ W2f, const float* __restrict__ root2,
                     ushort* __restrict__ Bt) {
  int i = blockIdx.x * 256 + threadIdx.x;
  if (i >= 112 * KTOT) return;
  int col = i / KTOT, kk = i - col * KTOT;
  float v = 0.f;
  if (kk < R2 * HID && col < HID) {
    int r = kk / HID, k = kk - r * HID;
    v = (r < NRELS) ? W2f[(r * HID + k) * HID + col] : root2[k * HID + col];
  }
  Bt[i] = f2bf(v);
}

// ---------------------------------------------------------------- conv1 aggregate
// 10 edge-groups x 25 channel-lanes (uint2 = 4 bf16 per load); LDS reduce.
__global__ __launch_bounds__(256) void k_agg1(const int* __restrict__ rowptr,
                                              const int* __restrict__ ebuf,
                                              const int* __restrict__ cnt_nr,
                                              const uint2* __restrict__ W1bf2,
                                              const float4* __restrict__ root1,
                                              const float4* __restrict__ bias1,
                                              float4* __restrict__ h4) {
  __shared__ f32x4 red[10][25];
  int n = blockIdx.x, t = threadIdx.x;
  int g = t / 25, c = t - g * 25;
  if (g < 10) {
    f32x4 a = (f32x4){0.f, 0.f, 0.f, 0.f};
    int beg = rowptr[n], end = rowptr[n + 1];
    for (int j = beg + g; j < end; j += 10) {
      int pk = ebuf[j];
      int r = pk & 63, s = pk >> 6;
      float cf = 1.0f / (float)cnt_nr[n * NRELS + r];
      uint2 u = W1bf2[(size_t)r * 250000 + s * 25 + c];
      a[0] += cf * bflo(u.x); a[1] += cf * bfhi(u.x);
      a[2] += cf * bflo(u.y); a[3] += cf * bfhi(u.y);
    }
    red[g][c] = a;
  }
  __syncthreads();
  if (t < 25) {
    f32x4 a = red[0][t];
#pragma unroll
    for (int g2 = 1; g2 < 10; ++g2) a += red[g2][t];
    float4 rt = root1[n * 25 + t];
    float4 bs = bias1[t];
    a += (f32x4){rt.x, rt.y, rt.z, rt.w};
    a += (f32x4){bs.x, bs.y, bs.z, bs.w};
#pragma unroll
    for (int q = 0; q < 4; ++q) if (a[q] < 0.f) a[q] = 0.f;
    h4[n * 25 + t] = make_float4(a[0], a[1], a[2], a[3]);
  }
}

// ---------------------------------------------------------------- hbar: segmented
// TWO tasks per wave (lanes 0-31 / 32-63, 25 active each); pack2bf HW cvt.
__global__ __launch_bounds__(512) void k_hseg(const int2* __restrict__ desc,
                                              const int* __restrict__ ebuf,
                                              const f32x4* __restrict__ h4,
                                              uint2* __restrict__ hbar2) {
  int wv = blockIdx.x * 8 + (threadIdx.x >> 6);
  int task = wv * 2 + ((threadIdx.x >> 5) & 1);
  if (task >= NN * R2) return;
  int n = task / R2, r = task - n * R2;
  int lane = threadIdx.x & 31;
  uint2* orow = hbar2 + (size_t)n * (KTOT / 4);   // 1056 uint2 per row
  if (r == NRELS) {   // root slot: copy h[n]
    if (lane < 25) {
      f32x4 v = h4[n * 25 + lane];
      orow[NRELS * 25 + lane] = make_uint2(pack2bf(v[0], v[1]), pack2bf(v[2], v[3]));
    }
    return;
  }
  int2 d = desc[n * NRELS + r];
  if (lane < 25) {
    f32x4 a = (f32x4){0.f, 0.f, 0.f, 0.f};
    for (int j = 0; j < d.y; ++j) {
      int s = ebuf[d.x + j] >> 6;
      a += h4[s * 25 + lane];
    }
    float coef = d.y ? 1.0f / (float)d.y : 0.f;
    a *= coef;
    orow[r * 25 + lane] = make_uint2(pack2bf(a[0], a[1]), pack2bf(a[2], a[3]));
  } else if (lane == 25 && r < 31) {
    orow[R2 * 25 + r] = make_uint2(0u, 0u);   // zero the 31-uint2 row tail
  }
}

// ---------------------------------------------------------------- split-K MFMA GEMM
// 2-phase double-buffered LDS pipeline (guide §5.5 T3-minimum).
__global__ __launch_bounds__(256) void k_gemm(const ushort* __restrict__ hbar,
                                              const ushort* __restrict__ Bt,
                                              float* __restrict__ part) {
  __shared__ char lds[2][12288];
  int t = threadIdx.x;
  int wid = t >> 6, l = t & 63;
  int lrow = l & 15, g16 = l >> 4;
  int kb0 = blockIdx.y * KB_PER;
  int row0 = blockIdx.x * 64;

  f32x4 acc[7];
#pragma unroll
  for (int j = 0; j < 7; ++j) acc[j] = (f32x4){0.f, 0.f, 0.f, 0.f};

  auto stage = [&](int p, int buf) {
    int kbg = kb0 + p;
#pragma unroll
    for (int ci = 0; ci < 3; ++ci) {
      int qb = (wid * 3 + ci) * 64;
      int q = qb + l;
      const ushort* g;
      if (q < 448) {                       // B chunk
        int col = q >> 2, c = q & 3;
        g = Bt + (size_t)col * KTOT + kbg * 32 + c * 8;
      } else if (q < 704) {                // A chunk
        int qq = q - 448;
        int row = qq >> 2, c = qq & 3;
        g = hbar + (size_t)(row0 + row) * KTOT + kbg * 32 + c * 8;
      } else {                             // pad
        g = Bt;
      }
      gload16(g, &lds[buf][(size_t)qb * 16]);
    }
  };

  stage(0, 0);
  __syncthreads();

  int cur = 0;
  for (int p = 0; p < KB_PER; ++p) {
    if (p + 1 < KB_PER) stage(p + 1, cur ^ 1);
    const char* base = lds[cur];
    bf16x8 a = *(const bf16x8*)(base + 7168 + (wid * 16 + lrow) * 64 + g16 * 16);
#pragma unroll
    for (int j = 0; j < 7; ++j) {
      bf16x8 b = *(const bf16x8*)(base + (j * 16 + lrow) * 64 + g16 * 16);
      acc[j] = __builtin_amdgcn_mfma_f32_16x16x32_bf16(a, b, acc[j], 0, 0, 0);
    }
    __syncthreads();
    cur ^= 1;
  }

  float* pp = part + (size_t)blockIdx.y * NROWS_PAD * 112;
  int srow = row0 + wid * 16 + g16 * 4;
#pragma unroll
  for (int j = 0; j < 7; ++j) {
    int col = j * 16 + lrow;
#pragma unroll
    for (int v = 0; v < 4; ++v)
      pp[(size_t)(srow + v) * 112 + col] = acc[j][v];
  }
}

// reduce partials + bias
__global__ void k_red(const float* __restrict__ part, const float* __restrict__ bias2,
                      float* __restrict__ xout) {
  int i = blockIdx.x * 256 + threadIdx.x;
  if (i >= NHTOT) return;
  int n = i / HID, c = i - n * HID;
  float s = bias2[c];
#pragma unroll
  for (int g = 0; g < SPLITK; ++g)
    s += part[(size_t)g * NROWS_PAD * 112 + (size_t)n * 112 + c];
  xout[i] = s;
}

// ---------------------------------------------------------------- rel_embedded
__global__ void k_emb(const float4* __restrict__ emb, const int* __restrict__ et,
                      float4* __restrict__ out2) {
  int i = blockIdx.x * 256 + threadIdx.x;
  if (i >= E_EDGES * 25) return;
  int e = i / 25, q = i - e * 25;
  int r = et[e];
  float4 v;
  if (r == 0) { v.x = 0.f; v.y = 0.f; v.z = 0.f; v.w = 0.f; }
  else v = emb[r * 25 + q];
  out2[i] = v;
}

// ---------------------------------------------------------------- launch
extern "C" void kernel_launch(void* const* d_in, const int* in_sizes, int n_in,
                              void* d_out, int out_size, void* d_ws, size_t ws_size,
                              hipStream_t stream) {
  (void)in_sizes; (void)n_in; (void)out_size; (void)d_ws; (void)ws_size;

  const float* comp1  = (const float*)d_in[0];
  const float* basis1 = (const float*)d_in[1];
  const float* root1  = (const float*)d_in[2];
  const float* bias1  = (const float*)d_in[3];
  const float* comp2  = (const float*)d_in[4];
  const float* basis2 = (const float*)d_in[5];
  const float* root2  = (const float*)d_in[6];
  const float* bias2  = (const float*)d_in[7];
  const float* emb    = (const float*)d_in[8];
  const int*   ei     = (const int*)d_in[9];
  const int*   et     = (const int*)d_in[10];
  const int* srcp = ei;
  const int* dstp = ei + E_EDGES;

  float* xout = (float*)d_out;
  float* scratch = xout + NHTOT;            // 32M floats (overwritten by k_emb last)
  int*   cnt_nr = (int*)scratch;            // @0          400,000
  int*   deg    = cnt_nr + 400000;          // @400,000     10,000
  int*   rowptr = deg + 10000;              // @410,000     10,004
  int*   fill_nr= rowptr + 10004;           // @420,004    400,000
  int2*  desc   = (int2*)(scratch + 820004);// @820,004    800,000 ints (even: 8B ok)
  int*   ebuf   = (int*)(scratch + 1620004);// @1,620,004  320,000 -> 1,940,004
  float* W2f    = scratch + 1940016;        // 400,000 -> 2,340,016
  ushort* Bt    = (ushort*)(scratch + 2340016);  // 236,544 f -> 2,576,560
  float* h      = scratch + 2576560;        // 1,000,000 -> 3,576,560
  uint*  W1bf   = (uint*)(scratch + 3576560);    // conv1 use: 20M
  uint*  hbar   = (uint*)(scratch + 3576560);    // conv2 use: 21,221,376 -> 24,797,936
  float* part   = scratch + 24797936;       // 4*10048*112 = 4,501,504 -> 29,299,440
  float* comp1t = scratch + 29400000;       // 1,200 -> 29,401,200 < 32M OK

  // zero cnt_nr / deg / fill_nr (rowptr, desc, ebuf fully written)
  hipMemsetAsync(cnt_nr, 0, (size_t)820004 * sizeof(int), stream);
  // zero the 48 pad rows of hbar so GEMM tail reads zeros
  hipMemsetAsync((char*)hbar + (size_t)NN * KTOT * 2, 0,
                 (size_t)(NROWS_PAD - NN) * KTOT * 2, stream);

  k_count <<<(E_EDGES + 255) / 256, 256, 0, stream>>>(dstp, et, cnt_nr, deg);
  k_scan  <<<1, 256, 0, stream>>>(deg, rowptr);
  k_pnr   <<<(NN + 255) / 256, 256, 0, stream>>>(cnt_nr, rowptr, desc);
  k_bucket<<<(E_EDGES + 255) / 256, 256, 0, stream>>>(srcp, dstp, et, desc,
                                                      fill_nr, ebuf);

  k_ct <<<(NRELS * NB + 255) / 256, 256, 0, stream>>>(comp1, comp1t);
  k_w2 <<<(HID * HID + 255) / 256, 256, 0, stream>>>(comp2, basis2, W2f);
  k_bt <<<(112 * KTOT + 255) / 256, 256, 0, stream>>>(W2f, root2, Bt);
  k_w1b<<<dim3((NHTOT / 4 + 255) / 256, RSPLIT), 256, 0, stream>>>(comp1t, basis1,
                                                                   (uint2*)W1bf);

  k_agg1<<<NN, 256, 0, stream>>>(rowptr, ebuf, cnt_nr, (const uint2*)W1bf,
                                 (const float4*)root1, (const float4*)bias1,
                                 (float4*)h);
  k_hseg<<<(NN * R2 + 15) / 16, 512, 0, stream>>>(desc, ebuf, (const f32x4*)h,
                                                  (uint2*)hbar);
  k_gemm<<<dim3(NROWS_PAD / 64, SPLITK), 256, 0, stream>>>((const ushort*)hbar, Bt, part);
  k_red <<<(NHTOT + 255) / 256, 256, 0, stream>>>(part, bias2, xout);

  k_emb<<<(E_EDGES * 25 + 255) / 256, 256, 0, stream>>>((const float4*)emb, et,
                                                        (float4*)(xout + NHTOT));
}

// Round 15
// 274.166 us; speedup vs baseline: 1.1935x; 1.1935x over previous
//
#include <hip/hip_runtime.h>
#include <hip/hip_bf16.h>
#include <cstdint>
#include <cstddef>

#define E_EDGES 320000
#define NN 10000
#define NRELS 40
#define NB 30
#define HID 100
#define NHTOT (NN*HID)       // 1,000,000
#define R2 41                // 40 rels + root2 slot
#define KTOT 4224            // 41*100 = 4100 packed, padded to 33*128
#define NROWS_PAD 10048      // 157 blocks * 64 rows
#define SPLITK 4             // 132 kb-steps -> 33 per gy
#define KB_PER 33

typedef short bf16x8 __attribute__((ext_vector_type(8)));
typedef float f32x4 __attribute__((ext_vector_type(4)));
typedef float f32x2 __attribute__((ext_vector_type(2)));

__device__ inline ushort f2bf(float f) {
  uint x = __float_as_uint(f);
  return (ushort)((x + 0x7fffu + ((x >> 16) & 1u)) >> 16);
}
__device__ inline float bflo(uint u) { return __uint_as_float(u << 16); }
__device__ inline float bfhi(uint u) { return __uint_as_float(u & 0xffff0000u); }

// HW packed f32->bf16 RNE (v_cvt_pk_bf16_f32 via compiler)
__device__ inline uint pack2bf(float x, float y) {
  union { __hip_bfloat162 b; uint u; } cv;
  cv.b = __float22bfloat162_rn(make_float2(x, y));
  return cv.u;
}

__device__ inline void gload16(const void* g, void* l) {
  __builtin_amdgcn_global_load_lds(
      (const __attribute__((address_space(1))) void*)g,
      (__attribute__((address_space(3))) void*)l, 16, 0, 0);
}

// ---------------------------------------------------------------- edge meta
__global__ void k_count(const int* __restrict__ dst, const int* __restrict__ et,
                        int* __restrict__ cnt_nr, int* __restrict__ deg) {
  int e = blockIdx.x * blockDim.x + threadIdx.x;
  if (e >= E_EDGES) return;
  int d = dst[e], r = et[e];
  atomicAdd(&cnt_nr[d * NRELS + r], 1);
  atomicAdd(&deg[d], 1);
}

__global__ void k_scan(const int* __restrict__ deg, int* __restrict__ rowptr) {
  __shared__ int ssum[256];
  int t = threadIdx.x;
  const int per = (NN + 255) / 256;
  int base = t * per;
  int s = 0;
  for (int k = 0; k < per; ++k) { int i = base + k; if (i < NN) s += deg[i]; }
  ssum[t] = s; __syncthreads();
  for (int off = 1; off < 256; off <<= 1) {
    int v = (t >= off) ? ssum[t - off] : 0;
    __syncthreads();
    ssum[t] += v;
    __syncthreads();
  }
  int pre = (t == 0) ? 0 : ssum[t - 1];
  for (int k = 0; k < per; ++k) {
    int i = base + k;
    if (i < NN) { rowptr[i] = pre; pre += deg[i]; }
  }
  if (t == 255) rowptr[NN] = ssum[255];
}

// per-node scan over rels -> task descriptors desc[n*40+r] = {segment begin, cnt}
__global__ void k_pnr(const int* __restrict__ cnt_nr, const int* __restrict__ rowptr,
                      int2* __restrict__ desc) {
  int n = blockIdx.x * 256 + threadIdx.x;
  if (n >= NN) return;
  int s = rowptr[n];
  for (int r = 0; r < NRELS; ++r) {
    int c = cnt_nr[n * NRELS + r];
    desc[n * NRELS + r] = make_int2(s, c);
    s += c;
  }
}

// bucket edges sorted by (dst, rel): segment-contiguous in ebuf
__global__ void k_bucket(const int* __restrict__ src, const int* __restrict__ dst,
                         const int* __restrict__ et, const int2* __restrict__ desc,
                         int* __restrict__ fill_nr, int* __restrict__ ebuf) {
  int e = blockIdx.x * blockDim.x + threadIdx.x;
  if (e >= E_EDGES) return;
  int d = dst[e], r = et[e];
  int pos = desc[d * NRELS + r].x + atomicAdd(&fill_nr[d * NRELS + r], 1);
  ebuf[pos] = (src[e] << 6) | r;
}

// comp1 transpose -> comp1t[b][r] (contiguous in r for wave-uniform s_load)
__global__ void k_ct(const float* __restrict__ comp1, float* __restrict__ comp1t) {
  int i = blockIdx.x * 256 + threadIdx.x;
  if (i >= NRELS * NB) return;
  int r = i / NB, b = i - r * NB;
  comp1t[b * NRELS + r] = comp1[i];
}

// ---------------------------------------------------------------- W1 (bf16)
// ONE float per thread: acc[40] = 40 VGPR (+v+addr ~52) fits under the 64-VGPR
// cap the allocator demonstrably grants with (256,2) -> no loop fission, basis1
// streamed exactly ONCE (r5-r14: any acc set >64 VGPR got fissioned, basis1
// re-streamed ~2x through L3, ~78us at ~4 TB/s served; single pass = 198 MB).
__global__ __launch_bounds__(256, 2) void k_w1b(const float* __restrict__ comp1t,
                                                const float* __restrict__ basis1,
                                                ushort* __restrict__ W1bs) {
  int i = blockIdx.x * 256 + threadIdx.x;
  if (i >= NHTOT) return;
  float acc[NRELS];
#pragma unroll
  for (int r = 0; r < NRELS; ++r) acc[r] = 0.f;
  for (int b = 0; b < NB; ++b) {
    float v = basis1[(size_t)b * NHTOT + i];
    const float* ct = comp1t + b * NRELS;   // wave-uniform -> s_load
#pragma unroll
    for (int r = 0; r < NRELS; ++r) acc[r] += ct[r] * v;
  }
#pragma unroll
  for (int r = 0; r < NRELS; ++r)
    W1bs[(size_t)r * NHTOT + i] = f2bf(acc[r]);
}

// ---------------------------------------------------------------- W2 fp32 then packed Bt bf16
__global__ void k_w2(const float* __restrict__ comp2, const float* __restrict__ basis2,
                     float* __restrict__ W2f) {
  int i = blockIdx.x * 256 + threadIdx.x;
  if (i >= HID * HID) return;
  float v[NB];
#pragma unroll
  for (int b = 0; b < NB; ++b) v[b] = basis2[b * HID * HID + i];
  for (int r = 0; r < NRELS; ++r) {
    float a = 0.f;
#pragma unroll
    for (int b = 0; b < NB; ++b) a += comp2[r * NB + b] * v[b];
    W2f[r * HID * HID + i] = a;
  }
}

// Bt[col][kk] packed K: kk = r*100 + k  (r<40: W2f[r][k][col], r==40: root2[k][col])
__global__ void k_bt(const float* __restrict__ W2f, const float* __restrict__ root2,
                     ushort* __restrict__ Bt) {
  int i = blockIdx.x * 256 + threadIdx.x;
  if (i >= 112 * KTOT) return;
  int col = i / KTOT, kk = i - col * KTOT;
  float v = 0.f;
  if (kk < R2 * HID && col < HID) {
    int r = kk / HID, k = kk - r * HID;
    v = (r < NRELS) ? W2f[(r * HID + k) * HID + col] : root2[k * HID + col];
  }
  Bt[i] = f2bf(v);
}

// ---------------------------------------------------------------- conv1 aggregate
// 10 edge-groups x 25 channel-lanes (uint2 = 4 bf16 per load); LDS reduce.
__global__ __launch_bounds__(256) void k_agg1(const int* __restrict__ rowptr,
                                              const int* __restrict__ ebuf,
                                              const int* __restrict__ cnt_nr,
                                              const uint2* __restrict__ W1bf2,
                                              const float4* __restrict__ root1,
                                              const float4* __restrict__ bias1,
                                              float4* __restrict__ h4) {
  __shared__ f32x4 red[10][25];
  int n = blockIdx.x, t = threadIdx.x;
  int g = t / 25, c = t - g * 25;
  if (g < 10) {
    f32x4 a = (f32x4){0.f, 0.f, 0.f, 0.f};
    int beg = rowptr[n], end = rowptr[n + 1];
    for (int j = beg + g; j < end; j += 10) {
      int pk = ebuf[j];
      int r = pk & 63, s = pk >> 6;
      float cf = 1.0f / (float)cnt_nr[n * NRELS + r];
      uint2 u = W1bf2[(size_t)r * 250000 + s * 25 + c];
      a[0] += cf * bflo(u.x); a[1] += cf * bfhi(u.x);
      a[2] += cf * bflo(u.y); a[3] += cf * bfhi(u.y);
    }
    red[g][c] = a;
  }
  __syncthreads();
  if (t < 25) {
    f32x4 a = red[0][t];
#pragma unroll
    for (int g2 = 1; g2 < 10; ++g2) a += red[g2][t];
    float4 rt = root1[n * 25 + t];
    float4 bs = bias1[t];
    a += (f32x4){rt.x, rt.y, rt.z, rt.w};
    a += (f32x4){bs.x, bs.y, bs.z, bs.w};
#pragma unroll
    for (int q = 0; q < 4; ++q) if (a[q] < 0.f) a[q] = 0.f;
    h4[n * 25 + t] = make_float4(a[0], a[1], a[2], a[3]);
  }
}

// ---------------------------------------------------------------- hbar: segmented
// TWO tasks per wave (lanes 0-31 / 32-63, 25 active each); pack2bf HW cvt.
__global__ __launch_bounds__(512) void k_hseg(const int2* __restrict__ desc,
                                              const int* __restrict__ ebuf,
                                              const f32x4* __restrict__ h4,
                                              uint2* __restrict__ hbar2) {
  int wv = blockIdx.x * 8 + (threadIdx.x >> 6);
  int task = wv * 2 + ((threadIdx.x >> 5) & 1);
  if (task >= NN * R2) return;
  int n = task / R2, r = task - n * R2;
  int lane = threadIdx.x & 31;
  uint2* orow = hbar2 + (size_t)n * (KTOT / 4);   // 1056 uint2 per row
  if (r == NRELS) {   // root slot: copy h[n]
    if (lane < 25) {
      f32x4 v = h4[n * 25 + lane];
      orow[NRELS * 25 + lane] = make_uint2(pack2bf(v[0], v[1]), pack2bf(v[2], v[3]));
    }
    return;
  }
  int2 d = desc[n * NRELS + r];
  if (lane < 25) {
    f32x4 a = (f32x4){0.f, 0.f, 0.f, 0.f};
    for (int j = 0; j < d.y; ++j) {
      int s = ebuf[d.x + j] >> 6;
      a += h4[s * 25 + lane];
    }
    float coef = d.y ? 1.0f / (float)d.y : 0.f;
    a *= coef;
    orow[r * 25 + lane] = make_uint2(pack2bf(a[0], a[1]), pack2bf(a[2], a[3]));
  } else if (lane == 25 && r < 31) {
    orow[R2 * 25 + r] = make_uint2(0u, 0u);   // zero the 31-uint2 row tail
  }
}

// ---------------------------------------------------------------- split-K MFMA GEMM
// 2-phase double-buffered LDS pipeline (guide §5.5 T3-minimum).
__global__ __launch_bounds__(256) void k_gemm(const ushort* __restrict__ hbar,
                                              const ushort* __restrict__ Bt,
                                              float* __restrict__ part) {
  __shared__ char lds[2][12288];
  int t = threadIdx.x;
  int wid = t >> 6, l = t & 63;
  int lrow = l & 15, g16 = l >> 4;
  int kb0 = blockIdx.y * KB_PER;
  int row0 = blockIdx.x * 64;

  f32x4 acc[7];
#pragma unroll
  for (int j = 0; j < 7; ++j) acc[j] = (f32x4){0.f, 0.f, 0.f, 0.f};

  auto stage = [&](int p, int buf) {
    int kbg = kb0 + p;
#pragma unroll
    for (int ci = 0; ci < 3; ++ci) {
      int qb = (wid * 3 + ci) * 64;
      int q = qb + l;
      const ushort* g;
      if (q < 448) {                       // B chunk
        int col = q >> 2, c = q & 3;
        g = Bt + (size_t)col * KTOT + kbg * 32 + c * 8;
      } else if (q < 704) {                // A chunk
        int qq = q - 448;
        int row = qq >> 2, c = qq & 3;
        g = hbar + (size_t)(row0 + row) * KTOT + kbg * 32 + c * 8;
      } else {                             // pad
        g = Bt;
      }
      gload16(g, &lds[buf][(size_t)qb * 16]);
    }
  };

  stage(0, 0);
  __syncthreads();

  int cur = 0;
  for (int p = 0; p < KB_PER; ++p) {
    if (p + 1 < KB_PER) stage(p + 1, cur ^ 1);
    const char* base = lds[cur];
    bf16x8 a = *(const bf16x8*)(base + 7168 + (wid * 16 + lrow) * 64 + g16 * 16);
#pragma unroll
    for (int j = 0; j < 7; ++j) {
      bf16x8 b = *(const bf16x8*)(base + (j * 16 + lrow) * 64 + g16 * 16);
      acc[j] = __builtin_amdgcn_mfma_f32_16x16x32_bf16(a, b, acc[j], 0, 0, 0);
    }
    __syncthreads();
    cur ^= 1;
  }

  float* pp = part + (size_t)blockIdx.y * NROWS_PAD * 112;
  int srow = row0 + wid * 16 + g16 * 4;
#pragma unroll
  for (int j = 0; j < 7; ++j) {
    int col = j * 16 + lrow;
#pragma unroll
    for (int v = 0; v < 4; ++v)
      pp[(size_t)(srow + v) * 112 + col] = acc[j][v];
  }
}

// reduce partials + bias
__global__ void k_red(const float* __restrict__ part, const float* __restrict__ bias2,
                      float* __restrict__ xout) {
  int i = blockIdx.x * 256 + threadIdx.x;
  if (i >= NHTOT) return;
  int n = i / HID, c = i - n * HID;
  float s = bias2[c];
#pragma unroll
  for (int g = 0; g < SPLITK; ++g)
    s += part[(size_t)g * NROWS_PAD * 112 + (size_t)n * 112 + c];
  xout[i] = s;
}

// ---------------------------------------------------------------- rel_embedded
__global__ void k_emb(const float4* __restrict__ emb, const int* __restrict__ et,
                      float4* __restrict__ out2) {
  int i = blockIdx.x * 256 + threadIdx.x;
  if (i >= E_EDGES * 25) return;
  int e = i / 25, q = i - e * 25;
  int r = et[e];
  float4 v;
  if (r == 0) { v.x = 0.f; v.y = 0.f; v.z = 0.f; v.w = 0.f; }
  else v = emb[r * 25 + q];
  out2[i] = v;
}

// ---------------------------------------------------------------- launch
extern "C" void kernel_launch(void* const* d_in, const int* in_sizes, int n_in,
                              void* d_out, int out_size, void* d_ws, size_t ws_size,
                              hipStream_t stream) {
  (void)in_sizes; (void)n_in; (void)out_size; (void)d_ws; (void)ws_size;

  const float* comp1  = (const float*)d_in[0];
  const float* basis1 = (const float*)d_in[1];
  const float* root1  = (const float*)d_in[2];
  const float* bias1  = (const float*)d_in[3];
  const float* comp2  = (const float*)d_in[4];
  const float* basis2 = (const float*)d_in[5];
  const float* root2  = (const float*)d_in[6];
  const float* bias2  = (const float*)d_in[7];
  const float* emb    = (const float*)d_in[8];
  const int*   ei     = (const int*)d_in[9];
  const int*   et     = (const int*)d_in[10];
  const int* srcp = ei;
  const int* dstp = ei + E_EDGES;

  float* xout = (float*)d_out;
  float* scratch = xout + NHTOT;            // 32M floats (overwritten by k_emb last)
  int*   cnt_nr = (int*)scratch;            // @0          400,000
  int*   deg    = cnt_nr + 400000;          // @400,000     10,000
  int*   rowptr = deg + 10000;              // @410,000     10,004
  int*   fill_nr= rowptr + 10004;           // @420,004    400,000
  int2*  desc   = (int2*)(scratch + 820004);// @820,004    800,000 ints (even: 8B ok)
  int*   ebuf   = (int*)(scratch + 1620004);// @1,620,004  320,000 -> 1,940,004
  float* W2f    = scratch + 1940016;        // 400,000 -> 2,340,016
  ushort* Bt    = (ushort*)(scratch + 2340016);  // 236,544 f -> 2,576,560
  float* h      = scratch + 2576560;        // 1,000,000 -> 3,576,560
  uint*  W1bf   = (uint*)(scratch + 3576560);    // conv1 use: 20M
  uint*  hbar   = (uint*)(scratch + 3576560);    // conv2 use: 21,221,376 -> 24,797,936
  float* part   = scratch + 24797936;       // 4*10048*112 = 4,501,504 -> 29,299,440
  float* comp1t = scratch + 29400000;       // 1,200 -> 29,401,200 < 32M OK

  // zero cnt_nr / deg / fill_nr (rowptr, desc, ebuf fully written)
  hipMemsetAsync(cnt_nr, 0, (size_t)820004 * sizeof(int), stream);
  // zero the 48 pad rows of hbar so GEMM tail reads zeros
  hipMemsetAsync((char*)hbar + (size_t)NN * KTOT * 2, 0,
                 (size_t)(NROWS_PAD - NN) * KTOT * 2, stream);

  k_count <<<(E_EDGES + 255) / 256, 256, 0, stream>>>(dstp, et, cnt_nr, deg);
  k_scan  <<<1, 256, 0, stream>>>(deg, rowptr);
  k_pnr   <<<(NN + 255) / 256, 256, 0, stream>>>(cnt_nr, rowptr, desc);
  k_bucket<<<(E_EDGES + 255) / 256, 256, 0, stream>>>(srcp, dstp, et, desc,
                                                      fill_nr, ebuf);

  k_ct <<<(NRELS * NB + 255) / 256, 256, 0, stream>>>(comp1, comp1t);
  k_w2 <<<(HID * HID + 255) / 256, 256, 0, stream>>>(comp2, basis2, W2f);
  k_bt <<<(112 * KTOT + 255) / 256, 256, 0, stream>>>(W2f, root2, Bt);
  k_w1b<<<(NHTOT + 255) / 256, 256, 0, stream>>>(comp1t, basis1, (ushort*)W1bf);

  k_agg1<<<NN, 256, 0, stream>>>(rowptr, ebuf, cnt_nr, (const uint2*)W1bf,
                                 (const float4*)root1, (const float4*)bias1,
                                 (float4*)h);
  k_hseg<<<(NN * R2 + 15) / 16, 512, 0, stream>>>(desc, ebuf, (const f32x4*)h,
                                                  (uint2*)hbar);
  k_gemm<<<dim3(NROWS_PAD / 64, SPLITK), 256, 0, stream>>>((const ushort*)hbar, Bt, part);
  k_red <<<(NHTOT + 255) / 256, 256, 0, stream>>>(part, bias2, xout);

  k_emb<<<(E_EDGES * 25 + 255) / 256, 256, 0, stream>>>((const float4*)emb, et,
                                                        (float4*)(xout + NHTOT));
}